// Round 6
// baseline (341.763 us; speedup 1.0000x reference)
//
#include <hip/hip_runtime.h>
#include <stdint.h>
#include <float.h>

// x[4096,256] f32, keys[65536,256] f32, values[65536,10] f32, k=8 (hardcoded).
#define B_ROWS 4096
#define N_KEYS 65536
#define DDIM 256
#define NCH 10

#define NSPLIT 16
#define SPLIT_KEYS (N_KEYS / NSPLIT)       // 4096
#define ROWS_PER_BLK 256
#define CHUNK_KEYS 64
#define NCHUNK (SPLIT_KEYS / CHUNK_KEYS)   // 64

typedef float f32x4 __attribute__((ext_vector_type(4)));
typedef short bf16x8 __attribute__((ext_vector_type(8)));

static __device__ __forceinline__ unsigned short f2bf(float f) {
  unsigned u = __float_as_uint(f);
  return (unsigned short)((u + 0x7FFFu + ((u >> 16) & 1u)) >> 16);
}
static __device__ __forceinline__ unsigned ford(float f) {
  unsigned u = __float_as_uint(f);
  return u ^ ((unsigned)((int)u >> 31) | 0x80000000u);
}
static __device__ __forceinline__ unsigned long long shfl_xor_u64(unsigned long long v, int m) {
  unsigned lo = __shfl_xor((unsigned)v, m, 64);
  unsigned hi = __shfl_xor((unsigned)(v >> 32), m, 64);
  return ((unsigned long long)hi << 32) | lo;
}
static __device__ __forceinline__ double shfl_xor_f64(double v, int m) {
  return __longlong_as_double((long long)shfl_xor_u64((unsigned long long)__double_as_longlong(v), m));
}
static __device__ __forceinline__ void gl_lds16(const void* g, void* l) {
  __builtin_amdgcn_global_load_lds(
      (const __attribute__((address_space(1))) unsigned int*)g,
      (__attribute__((address_space(3))) unsigned int*)l, 16, 0, 0);
}

// ---------------------------------------------------------------------------
// transpose_keys: bf16-convert + transpose + fused ksq. Output: per 64-key
// record [doct 0..31][key 0..63][16B] (32KB) so knn_main staging is a LINEAR
// copy and A-frag ds_read_b128s are 256B-contiguous per 16-lane phase.
// ---------------------------------------------------------------------------
__global__ __launch_bounds__(256) void transpose_keys(const float* __restrict__ keys,
                                                      unsigned char* __restrict__ kbf,
                                                      float* __restrict__ ksq) {
  __shared__ __align__(16) unsigned char T[128 * 512];
  const int t = threadIdx.x;
  const int lane = t & 63;
  const float4* src = (const float4*)(keys + (size_t)blockIdx.x * 128 * DDIM);
#pragma unroll
  for (int j = 0; j < 32; ++j) {
    int g = j * 256 + t;
    float4 v = src[g];
    int key = g >> 6;
    int u = lane >> 1, sub = lane & 1;
    unsigned lo = ((unsigned)f2bf(v.y) << 16) | f2bf(v.x);
    unsigned hi2 = ((unsigned)f2bf(v.w) << 16) | f2bf(v.z);
    unsigned long long p = ((unsigned long long)hi2 << 32) | lo;
    *(unsigned long long*)&T[key * 512 + ((u ^ (key & 7)) << 4) + (sub << 3)] = p;
    float ss = v.x * v.x + v.y * v.y + v.z * v.z + v.w * v.w;
#pragma unroll
    for (int off = 32; off; off >>= 1) ss += __shfl_xor(ss, off, 64);
    if (lane == 0) ksq[blockIdx.x * 128 + key] = ss;
  }
  __syncthreads();
  uint4* dst = (uint4*)(kbf + (size_t)blockIdx.x * 65536);
#pragma unroll
  for (int j = 0; j < 16; ++j) {
    int ou = j * 256 + t;
    int c64 = ou >> 11, rem = ou & 2047;
    int koct = rem >> 6, key64 = rem & 63;
    int keyl = c64 * 64 + key64;
    dst[ou] = *(const uint4*)&T[keyl * 512 + ((koct ^ (keyl & 7)) << 4)];
  }
}

// ---------------------------------------------------------------------------
// knn_main: 512 thr = 8 waves = 2 key-groups (kg, 32 keys) x 4 row-quads
// (rq, 64 rows = 4 register row-sets of 16). Block: 256 rows x one split
// (4096 keys) in 64 chunks of 64 keys. 1 block/CU, ~2 waves/SIMD.
// feed-4: each A-frag ds_read_b128 feeds 4 MFMAs (4 row-sets in registers).
// Counted-vmcnt double buffer: vmcnt(6) at tile entry (next chunk's 4 stage
// + 2 ksq loads in flight), lgkmcnt(0) at exit. Never drains in the loop.
// Selection: tau filter + append (r5 scheme). Streams per row = (hi x kg)
// = 8 exactly; tau_row = max of the 8 stream minima >= row's true 8th-best
// at all times; any score <= tau appended to per-(row,split) pool; overflow
// (count > CAP) triggers exact rescan in refine, so correctness is
// unconditional.
// ---------------------------------------------------------------------------
__global__ __launch_bounds__(512, 2) void knn_main(
    const float* __restrict__ x,
    const unsigned char* __restrict__ kbf,
    const float* __restrict__ ksqg,
    unsigned int* __restrict__ pools,
    unsigned int* __restrict__ counts,
    int CAP) {
  __shared__ __align__(16) unsigned char tiles[2][32768]; // 64KB double buffer
  __shared__ float tauh[2][256];                          // [kg][row]
  __shared__ unsigned int rowcnt[256];

  const int t = threadIdx.x;
  const int lane = t & 63;
  const int wv = t >> 6;       // 0..7
  const int kg = wv & 1;       // key group (32 keys)
  const int rq = wv >> 1;      // row quarter (64 rows)
  const int lo4 = lane & 15;
  const int hi = lane >> 4;

  const int split = blockIdx.x & (NSPLIT - 1);
  const int rb = (blockIdx.x >> 4) * ROWS_PER_BLK;
  const int sb = split * SPLIT_KEYS;

  // ---- x fragments: 4 row-sets of 16 rows, resident all kernel (128 VGPR)
  bf16x8 xb[4][8];
#pragma unroll
  for (int st = 0; st < 4; ++st) {
    const float* xr = x + (size_t)(rb + rq * 64 + st * 16 + lo4) * DDIM;
#pragma unroll
    for (int s = 0; s < 8; ++s) {
      const float* p = xr + s * 32 + hi * 8;
      float4 a = *(const float4*)p, b = *(const float4*)(p + 4);
      union { unsigned short us[8]; bf16x8 v; } u;
      u.us[0]=f2bf(a.x); u.us[1]=f2bf(a.y); u.us[2]=f2bf(a.z); u.us[3]=f2bf(a.w);
      u.us[4]=f2bf(b.x); u.us[5]=f2bf(b.y); u.us[6]=f2bf(b.z); u.us[7]=f2bf(b.w);
      xb[st][s] = u.v;
    }
  }

  if (t < 256) rowcnt[t] = 0;

  const unsigned char* srcbase = kbf + ((size_t)(split * NCHUNK) << 15);

  auto STAGE = [&](int c, int buf) { // linear 32KB, 4 x 16B per thread
    const unsigned char* src = srcbase + ((size_t)c << 15);
    unsigned char* wb = (unsigned char*)tiles[buf] + ((wv * 64) << 4);
#pragma unroll
    for (int i = 0; i < 4; ++i)
      gl_lds16(src + (((i * 512) + t) << 4), wb + ((i * 512) << 4));
  };

  const int kqoff = kg * 32 + hi * 4;
  float4 kqc0 = *(const float4*)(ksqg + sb + kqoff);
  float4 kqc1 = *(const float4*)(ksqg + sb + kqoff + 16);

  float smin[4] = {FLT_MAX, FLT_MAX, FLT_MAX, FLT_MAX};
  f32x4 acc[4][2];

  auto COMPUTE = [&](int c) {
    const unsigned char* tile = tiles[c & 1];
#pragma unroll
    for (int st = 0; st < 4; ++st) { acc[st][0] = 0.0f; acc[st][1] = 0.0f; }
#pragma unroll
    for (int s = 0; s < 8; ++s) {
      const unsigned char* rp = tile + (s * 4 + hi) * 1024 + (kg * 32 + lo4) * 16;
      bf16x8 af0 = *(const bf16x8*)rp;
      bf16x8 af1 = *(const bf16x8*)(rp + 256);
#pragma unroll
      for (int st = 0; st < 4; ++st) {
        acc[st][0] = __builtin_amdgcn_mfma_f32_16x16x32_bf16(af0, xb[st][s], acc[st][0], 0, 0, 0);
        acc[st][1] = __builtin_amdgcn_mfma_f32_16x16x32_bf16(af1, xb[st][s], acc[st][1], 0, 0, 0);
      }
    }
  };

  auto SELECT = [&](int c, const float* trd) { // scores + smin + gated append
    const int kbase = c * CHUNK_KEYS + kg * 32;
#pragma unroll
    for (int st = 0; st < 4; ++st) {
      float sc[8];
#pragma unroll
      for (int i = 0; i < 4; ++i) {
        sc[i]     = fmaf(-2.0f, acc[st][0][i], ((const float*)&kqc0)[i]);
        sc[4 + i] = fmaf(-2.0f, acc[st][1][i], ((const float*)&kqc1)[i]);
      }
      float m = sc[0];
#pragma unroll
      for (int e = 1; e < 8; ++e) m = fminf(m, sc[e]);
      smin[st] = fminf(smin[st], m);
      if (m <= trd[st]) { // rare
        const int lrow = rq * 64 + st * 16 + lo4;
        const size_t pb = ((size_t)(rb + lrow) * NSPLIT + split) * (size_t)CAP;
#pragma unroll
        for (int e = 0; e < 8; ++e) {
          if (sc[e] <= trd[st]) {
            unsigned slot = atomicAdd(&rowcnt[lrow], 1u);
            if ((int)slot < CAP)
              pools[pb + slot] = (ford(sc[e]) & 0xFFFFF000u)
                               | (unsigned)(kbase + (e >> 2) * 16 + hi * 4 + (e & 3));
          }
        }
      }
    }
  };

  auto PUBLISH = [&]() {
#pragma unroll
    for (int st = 0; st < 4; ++st) {
      float v = smin[st];
      v = fmaxf(v, __shfl_xor(v, 16, 64));
      v = fmaxf(v, __shfl_xor(v, 32, 64)); // max over the 4 hi-stream minima
      if (hi == 0) tauh[kg][rq * 64 + st * 16 + lo4] = v;
    }
  };

  // ---- prologue + peeled chunk 0 (no appends before tau exists)
  STAGE(0, 0);
  __syncthreads();

  STAGE(1, 1);
  float4 kqn0 = *(const float4*)(ksqg + sb + 64 + kqoff);
  float4 kqn1 = *(const float4*)(ksqg + sb + 64 + kqoff + 16);
  COMPUTE(0);
  {
    float tneg[4] = {-FLT_MAX, -FLT_MAX, -FLT_MAX, -FLT_MAX};
    SELECT(0, tneg); // smin only, gate never fires
  }
  PUBLISH();
  __syncthreads(); // tau visible (also drains stage(1) — prologue only)
  {
    float trd[4];
#pragma unroll
    for (int st = 0; st < 4; ++st) {
      int lr = rq * 64 + st * 16 + lo4;
      trd[st] = fmaxf(tauh[0][lr], tauh[1][lr]);
    }
    SELECT(0, trd); // append chunk 0 with fresh tau
  }
  kqc0 = kqn0; kqc1 = kqn1;

#pragma unroll 1
  for (int c = 1; c < NCHUNK; ++c) {
    const int cn = (c + 1 < NCHUNK) ? c + 1 : c; // uniform tail (re-stage ok)
    STAGE(cn, (c + 1) & 1);
    float4 kn0 = *(const float4*)(ksqg + sb + cn * 64 + kqoff);
    float4 kn1 = *(const float4*)(ksqg + sb + cn * 64 + kqoff + 16);
    float trd[4];
#pragma unroll
    for (int st = 0; st < 4; ++st) {
      int lr = rq * 64 + st * 16 + lo4;
      trd[st] = fmaxf(tauh[0][lr], tauh[1][lr]); // lagged tau: valid bound
    }
    asm volatile("s_waitcnt vmcnt(6)" ::: "memory"); // chunk c landed; c+1 in flight
    __builtin_amdgcn_s_barrier();
    __builtin_amdgcn_sched_barrier(0);
    COMPUTE(c);
    SELECT(c, trd);
    PUBLISH();
    kqc0 = kn0; kqc1 = kn1;
    asm volatile("s_waitcnt lgkmcnt(0)" ::: "memory"); // tile reads + tau writes done
    __builtin_amdgcn_s_barrier();
  }

  __syncthreads();
  if (t < 256) counts[(size_t)(rb + t) * NSPLIT + split] = rowcnt[t];
}

// ---------------------------------------------------------------------------
// knn_refine: per row (1 wave): scan the row's 16 pools (or exact-rescan any
// overflowed split) into per-lane top-8, tournament top-24 by quantized
// score, fp64-exact recompute, true top-8 (idx tiebreak), average values.
// ---------------------------------------------------------------------------
__global__ __launch_bounds__(64) void knn_refine(
    const float* __restrict__ x,
    const float* __restrict__ keys,
    const float* __restrict__ ksq,
    const float* __restrict__ values,
    const unsigned int* __restrict__ pools,
    const unsigned int* __restrict__ counts,
    int CAP,
    float* __restrict__ out) {
  __shared__ float4 xl[64];
  const int row = blockIdx.x;
  const int lane = threadIdx.x;

  xl[lane] = ((const float4*)(x + (size_t)row * DDIM))[lane];
  __syncthreads();

  unsigned long long h[8];
#pragma unroll
  for (int i = 0; i < 8; ++i) h[i] = ~0ULL;

  auto insert = [&](unsigned long long v) {
    if (v < h[7]) {
#pragma unroll
      for (int j = 7; j >= 1; --j) {
        unsigned long long a = h[j - 1];
        unsigned long long mx = a > v ? a : v;
        h[j] = (v < h[j]) ? mx : h[j];
      }
      h[0] = h[0] < v ? h[0] : v;
    }
  };

  for (int s = 0; s < NSPLIT; ++s) {
    unsigned cnt = counts[(size_t)row * NSPLIT + s];
    if ((int)cnt <= CAP) {
      const unsigned int* pp = pools + ((size_t)row * NSPLIT + s) * (size_t)CAP;
      for (int i = lane; i < (int)cnt; i += 64) {
        unsigned p = pp[i];
        unsigned long long v = ((unsigned long long)p << 16)
                             | (unsigned)(s * SPLIT_KEYS + (p & 0xFFFu));
        insert(v);
      }
    } else {
      // overflow fallback: exact fp32 rescan of this split
      for (int kk = lane; kk < SPLIT_KEYS; kk += 64) {
        int gk = s * SPLIT_KEYS + kk;
        const float4* kr = (const float4*)(keys + (size_t)gk * DDIM);
        float acc = 0.f;
#pragma unroll 8
        for (int d = 0; d < 64; ++d) {
          float4 kv = kr[d], xv = xl[d];
          acc = fmaf(kv.x, xv.x, acc); acc = fmaf(kv.y, xv.y, acc);
          acc = fmaf(kv.z, xv.z, acc); acc = fmaf(kv.w, xv.w, acc);
        }
        float sc = fmaf(-2.0f, acc, ksq[gk]);
        unsigned p = (ford(sc) & 0xFFFFF000u) | (unsigned)kk;
        insert(((unsigned long long)p << 16) | (unsigned)gk);
      }
    }
  }

  // ---- tournament: top-24 by quantized score (u64 unique: gk in low bits)
  int myidx = 0;
#pragma unroll 1
  for (int r = 0; r < 24; ++r) {
    unsigned long long m = h[0];
#pragma unroll
    for (int off = 32; off; off >>= 1) {
      unsigned long long o = shfl_xor_u64(m, off);
      m = o < m ? o : m;
    }
    if (lane == r) myidx = (int)(m & 0xFFFFu);
    if (h[0] == m) {
#pragma unroll
      for (int i = 0; i < 7; ++i) h[i] = h[i + 1];
      h[7] = ~0ULL;
    }
  }

  // ---- exact fp64 distance for my candidate
  double dv = 1e300;
  if (lane < 24) {
    const float4* kr = (const float4*)(keys + (size_t)myidx * DDIM);
    double s = 0.0;
#pragma unroll 8
    for (int d = 0; d < 64; ++d) {
      float4 kv = kr[d], xv = xl[d];
      double d0 = (double)xv.x - (double)kv.x;
      double d1 = (double)xv.y - (double)kv.y;
      double d2 = (double)xv.z - (double)kv.z;
      double d3 = (double)xv.w - (double)kv.w;
      s += d0 * d0 + d1 * d1 + d2 * d2 + d3 * d3;
    }
    dv = s;
  }

  int di = myidx;
  int chosen[8];
#pragma unroll
  for (int r = 0; r < 8; ++r) {
    double m = dv; int mi = di;
#pragma unroll
    for (int off = 32; off; off >>= 1) {
      double om = shfl_xor_f64(m, off);
      int omi = __shfl_xor(mi, off, 64);
      if (om < m || (om == m && omi < mi)) { m = om; mi = omi; }
    }
    chosen[r] = mi;
    if (di == mi && dv < 1e300) dv = 1e300;
  }

  if (lane < NCH) {
    double a = 0.0;
#pragma unroll
    for (int r = 0; r < 8; ++r) a += (double)values[(size_t)chosen[r] * NCH + lane];
    out[row * NCH + lane] = (float)(a * 0.125);
  }
}

// ---------------------------------------------------------------------------
extern "C" void kernel_launch(void* const* d_in, const int* in_sizes, int n_in,
                              void* d_out, int out_size, void* d_ws, size_t ws_size,
                              hipStream_t stream) {
  (void)in_sizes; (void)n_in; (void)out_size;
  const float* x      = (const float*)d_in[0];
  const float* keys   = (const float*)d_in[1];
  const float* values = (const float*)d_in[2];
  float* out = (float*)d_out;

  char* ws = (char*)d_ws;
  unsigned char* kbf = (unsigned char*)ws;                     // 32 MB transposed bf16 keys
  float* ksq   = (float*)(ws + 33554432);                      // 256 KB
  unsigned int* counts = (unsigned int*)(ws + 33554432 + 262144); // 256 KB (4096*16*4)
  unsigned int* pools  = (unsigned int*)(ws + 33554432 + 262144 + 262144);

  size_t base = 33554432 + 262144 + 262144;
  size_t cap = (ws_size > base) ? (ws_size - base) / ((size_t)B_ROWS * NSPLIT * 4) : 32;
  if (cap < 32) cap = 32;
  if (cap > 1024) cap = 1024;
  int CAP = (int)cap;

  transpose_keys<<<N_KEYS / 128, 256, 0, stream>>>(keys, kbf, ksq);
  knn_main<<<(B_ROWS / ROWS_PER_BLK) * NSPLIT, 512, 0, stream>>>(
      x, kbf, ksq, pools, counts, CAP);
  knn_refine<<<B_ROWS, 64, 0, stream>>>(x, keys, ksq, values, pools, counts, CAP, out);
}